// Round 1
// baseline (157.552 us; speedup 1.0000x reference)
//
#include <hip/hip_runtime.h>

// DiscriminatorIndependent: 1024 tiny MLPs (2->4->1, relu), B=16384.
//
// R5: drop the LDS staging round-trip entirely. Map thread t to the 4
// CONSECUTIVE MLPs 4t..4t+3 so the payload loads (x, xa) are coalesced
// float4 row reads (1 KB/wave/instr) straight into registers -- unlike the
// R1-R4 register variants, which were column-strided scalar loads and hence
// latency-serialized. One 256-thread block covers the whole 1024-MLP axis
// for ROWS=8 batch rows: params (65 floats) stay in VGPRs for all 8 rows,
// the 8 row iterations are independent FMA chains (compiler can keep
// multiple dwordx4 pairs in flight, no barrier in the loop), and the
// reduction is one LDS transpose + 6 shfl per row instead of 96 shfl/thread.
// out[b] is written exactly once by its owner block: no atomics, no
// zero_out kernel.

constexpr int N_MLP = 1024;
constexpr int BATCH = 16384;
constexpr int ROWS = 8;        // batch rows per block
constexpr int NTHREADS = 256;  // 4 waves; 256 threads x 4 MLPs = all 1024

__global__ __launch_bounds__(NTHREADS, 4)
void disc_mlp_kernel(const float* __restrict__ x,
                     const float* __restrict__ xa,
                     const float* __restrict__ W1,
                     const float* __restrict__ b1,
                     const float* __restrict__ W2,
                     const float* __restrict__ b2,
                     float* __restrict__ out)
{
    __shared__ float red[ROWS][NTHREADS];   // 8 KB

    const int t    = threadIdx.x;
    const int lane = t & 63;
    const int wave = t >> 6;
    const int b0   = blockIdx.x * ROWS;
    const int m0   = t * 4;                 // first of this thread's 4 MLPs

    // ---- params for 4 consecutive MLPs -> 65 registers ----
    // W1[m] is 8 floats [h][e]: q0 = (h0e0,h0e1,h1e0,h1e1), q1 = (h2e0,...)
    float4 q0[4], q1[4], bv[4], wv[4];
#pragma unroll
    for (int m = 0; m < 4; ++m) {
        q0[m] = reinterpret_cast<const float4*>(W1)[(size_t)(m0 + m) * 2];
        q1[m] = reinterpret_cast<const float4*>(W1)[(size_t)(m0 + m) * 2 + 1];
        bv[m] = reinterpret_cast<const float4*>(b1)[m0 + m];
        wv[m] = reinterpret_cast<const float4*>(W2)[m0 + m];
    }
    const float4 b2v = reinterpret_cast<const float4*>(b2)[t];
    const float bsum = (b2v.x + b2v.y) + (b2v.z + b2v.w);

    const float4* xp = reinterpret_cast<const float4*>(x  + (size_t)b0 * N_MLP) + t;
    const float4* ap = reinterpret_cast<const float4*>(xa + (size_t)b0 * N_MLP) + t;
    constexpr int STRIDE4 = N_MLP / 4;      // 256 float4 per row

    // ---- stream ROWS rows; independent chains, no barriers ----
    float acc[ROWS];
#pragma unroll
    for (int r = 0; r < ROWS; ++r) {
        const float4 xv = xp[r * STRIDE4];
        const float4 av = ap[r * STRIDE4];
        const float xe[4] = {xv.x, xv.y, xv.z, xv.w};
        const float ae[4] = {av.x, av.y, av.z, av.w};
        float s = bsum;
#pragma unroll
        for (int m = 0; m < 4; ++m) {
            float h0 = fmaf(q0[m].x, xe[m], fmaf(q0[m].y, ae[m], bv[m].x));
            float h1 = fmaf(q0[m].z, xe[m], fmaf(q0[m].w, ae[m], bv[m].y));
            float h2 = fmaf(q1[m].x, xe[m], fmaf(q1[m].y, ae[m], bv[m].z));
            float h3 = fmaf(q1[m].z, xe[m], fmaf(q1[m].w, ae[m], bv[m].w));
            h0 = fmaxf(h0, 0.0f);
            h1 = fmaxf(h1, 0.0f);
            h2 = fmaxf(h2, 0.0f);
            h3 = fmaxf(h3, 0.0f);
            s = fmaf(wv[m].x, h0, s);
            s = fmaf(wv[m].y, h1, s);
            s = fmaf(wv[m].z, h2, s);
            s = fmaf(wv[m].w, h3, s);
        }
        acc[r] = s;
    }

    // ---- block reduction: LDS transpose, then 2 rows per wave ----
#pragma unroll
    for (int r = 0; r < ROWS; ++r) red[r][t] = acc[r];
    __syncthreads();

#pragma unroll
    for (int k = 0; k < ROWS / 4; ++k) {
        const int r = wave * (ROWS / 4) + k;
        float v = (red[r][lane] + red[r][lane + 64]) +
                  (red[r][lane + 128] + red[r][lane + 192]);
        v += __shfl_down(v, 32);
        v += __shfl_down(v, 16);
        v += __shfl_down(v, 8);
        v += __shfl_down(v, 4);
        v += __shfl_down(v, 2);
        v += __shfl_down(v, 1);
        if (lane == 0) out[b0 + r] = v * (1.0f / (float)N_MLP);
    }
}

extern "C" void kernel_launch(void* const* d_in, const int* in_sizes, int n_in,
                              void* d_out, int out_size, void* d_ws, size_t ws_size,
                              hipStream_t stream) {
    const float* x  = (const float*)d_in[0];
    const float* xa = (const float*)d_in[1];
    const float* W1 = (const float*)d_in[2];
    const float* b1 = (const float*)d_in[3];
    const float* W2 = (const float*)d_in[4];
    const float* b2 = (const float*)d_in[5];
    float* out = (float*)d_out;

    disc_mlp_kernel<<<BATCH / ROWS, NTHREADS, 0, stream>>>(x, xa, W1, b1, W2, b2, out);
}

// Round 2
// 148.461 us; speedup vs baseline: 1.0612x; 1.0612x over previous
//
#include <hip/hip_runtime.h>

// DiscriminatorIndependent: 1024 tiny MLPs (2->4->1, relu), B=16384.
//
// R1-R5 lesson (R5 re-confirmed): register-resident payload loads are
// latency-serialized by the compiler (VGPR=48 < what pipelining needs ->
// ~2 loads in flight -> 13% VALUBusy). Async global->LDS staging via
// __builtin_amdgcn_global_load_lds(width=16) has no VGPR destination, so
// all staging requests issue back-to-back.
//
// R6 vs R0 (42us): ROWS 16->8 cuts LDS 33KB->16.6KB -> occupancy goes
// 4 -> 8 blocks/CU (wave-limited, 100%). The __syncthreads() vmcnt-drain
// bubble in each block is now covered by 7 other resident blocks instead
// of 3. Reduction cost halves (96 -> 48 shfl/thread). Params re-load per
// block doubles but is L2-resident (68KB total) - off the critical path.

constexpr int N_MLP = 1024;
constexpr int BATCH = 16384;
constexpr int ROWS = 8;        // batch rows per block
constexpr int NTHREADS = 256;  // 4 waves; covers QN MLPs
constexpr int QN = 256;        // MLPs per block (quarter of N)
constexpr int NQ = N_MLP / QN; // 4 quarters

typedef __attribute__((address_space(3))) void lds_void;
typedef const __attribute__((address_space(1))) void gbl_void;

__global__ __launch_bounds__(256)
void zero_out_kernel(float* __restrict__ out) {
    out[blockIdx.x * 256 + threadIdx.x] = 0.0f;
}

__global__ __launch_bounds__(NTHREADS, 8)
void disc_mlp_kernel(const float* __restrict__ x,
                     const float* __restrict__ xa,
                     const float* __restrict__ W1,
                     const float* __restrict__ b1,
                     const float* __restrict__ W2,
                     const float* __restrict__ b2,
                     float* __restrict__ out)
{
    __shared__ float xbuf[ROWS * QN];   // 8 KB
    __shared__ float abuf[ROWS * QN];   // 8 KB
    __shared__ float red[NTHREADS / 64][ROWS];

    const int t    = threadIdx.x;
    const int lane = t & 63;
    const int wave = t >> 6;
    const int q  = blockIdx.x & (NQ - 1);  // n-quarter
    const int rb = blockIdx.x >> 2;        // row tile
    const int b0 = rb * ROWS;
    const int n  = q * QN + t;             // this thread's MLP

    // ---- this MLP's params -> 17 registers (L2-resident, overlaps staging) ----
    const float4 p0 = reinterpret_cast<const float4*>(W1)[(size_t)n * 2];
    const float4 p1 = reinterpret_cast<const float4*>(W1)[(size_t)n * 2 + 1];
    const float4 bb = reinterpret_cast<const float4*>(b1)[n];
    const float4 ww = reinterpret_cast<const float4*>(W2)[n];
    const float  b2r = b2[n];

    // ---- async global->LDS staging: each wave stages 2 rows of x and xa ----
    // Per (wave,row): 64 lanes x 16B = 1KB = one 256-float quarter-row.
    const float* gx = x  + (size_t)b0 * N_MLP + q * QN;
    const float* ga = xa + (size_t)b0 * N_MLP + q * QN;
#pragma unroll
    for (int i = 0; i < ROWS / 4; ++i) {
        const int r = wave * (ROWS / 4) + i;
        const float* srcx = gx + (size_t)r * N_MLP + lane * 4;
        const float* srca = ga + (size_t)r * N_MLP + lane * 4;
        __builtin_amdgcn_global_load_lds((gbl_void*)srcx,
                                         (lds_void*)&xbuf[r * QN + lane * 4],
                                         16, 0, 0);
        __builtin_amdgcn_global_load_lds((gbl_void*)srca,
                                         (lds_void*)&abuf[r * QN + lane * 4],
                                         16, 0, 0);
    }
    __syncthreads();   // drains vmcnt: all 16 KB resident

    const float A[4]   = {p0.x, p0.z, p1.x, p1.z};
    const float C[4]   = {p0.y, p0.w, p1.y, p1.w};
    const float B1r[4] = {bb.x, bb.y, bb.z, bb.w};
    const float V[4]   = {ww.x, ww.y, ww.z, ww.w};

    // ---- compute from LDS ----
    float acc[ROWS];
#pragma unroll
    for (int r = 0; r < ROWS; ++r) {
        const float xe  = xbuf[r * QN + t];
        const float xae = abuf[r * QN + t];
        float s = b2r;
#pragma unroll
        for (int j = 0; j < 4; ++j) {
            float h = fmaf(A[j], xe, fmaf(C[j], xae, B1r[j]));
            h = fmaxf(h, 0.0f);
            s = fmaf(V[j], h, s);
        }
        acc[r] = s;
    }

    // ---- reduce each row across the block's 256 threads ----
#pragma unroll
    for (int r = 0; r < ROWS; ++r) {
        float v = acc[r];
        v += __shfl_down(v, 32);
        v += __shfl_down(v, 16);
        v += __shfl_down(v, 8);
        v += __shfl_down(v, 4);
        v += __shfl_down(v, 2);
        v += __shfl_down(v, 1);
        if (lane == 0) red[wave][r] = v;
    }
    __syncthreads();
    if (t < ROWS) {
        float s = (red[0][t] + red[1][t]) + (red[2][t] + red[3][t]);
        atomicAdd(out + b0 + t, s * (1.0f / (float)N_MLP));
    }
}

extern "C" void kernel_launch(void* const* d_in, const int* in_sizes, int n_in,
                              void* d_out, int out_size, void* d_ws, size_t ws_size,
                              hipStream_t stream) {
    const float* x  = (const float*)d_in[0];
    const float* xa = (const float*)d_in[1];
    const float* W1 = (const float*)d_in[2];
    const float* b1 = (const float*)d_in[3];
    const float* W2 = (const float*)d_in[4];
    const float* b2 = (const float*)d_in[5];
    float* out = (float*)d_out;

    zero_out_kernel<<<BATCH / 256, 256, 0, stream>>>(out);
    disc_mlp_kernel<<<(BATCH / ROWS) * NQ, NTHREADS, 0, stream>>>(x, xa, W1, b1, W2, b2, out);
}